// Round 1
// baseline (701.897 us; speedup 1.0000x reference)
//
#include <hip/hip_runtime.h>
#include <hip/hip_bf16.h>
#include <cstdint>
#include <cstddef>

#define NV 50000
#define ED 128
#define SS 50
#define NB 128
#define NM 200
#define BMD (NB*NM*ED)   // 3,276,800 floats per table

// ---------------------------------------------------------------------------
// Kernel A: M_k[b][m][d] = sum_s enc[s][d] * C[k][story[b][m][s]][d], k=0..3
// One wave (64 lanes) per (b,m); each lane handles 2 d's via float2.
// ---------------------------------------------------------------------------
__global__ __launch_bounds__(256) void story_embed_k(
    const int* __restrict__ story, const float* __restrict__ C,
    float* __restrict__ Mt) {
  const int wave = threadIdx.x >> 6;
  const int lane = threadIdx.x & 63;
  const int bm = blockIdx.x * 4 + wave;          // < 25600
  const int* idx = story + (size_t)bm * SS;
  int myidx = (lane < SS) ? idx[lane] : 0;       // lane l holds idx[l]
  const float a0 = (float)(2*lane + 1) - 64.5f;  // (d+1) - (D+1)/2, d = 2*lane
  const float a1 = (float)(2*lane + 2) - 64.5f;
  float2 acc[4];
#pragma unroll
  for (int k = 0; k < 4; ++k) { acc[k].x = 0.f; acc[k].y = 0.f; }
  for (int s = 0; s < SS; ++s) {
    int row = __shfl(myidx, s);                  // broadcast idx[s]
    float e0, e1;
    if (s == SS - 1) { e0 = 1.0f; e1 = 1.0f; }
    else {
      float js = (float)(s + 1) - 25.5f;
      e0 = 1.0f + a0 * js * 6.25e-4f;            // 4/(128*50) = 6.25e-4
      e1 = 1.0f + a1 * js * 6.25e-4f;
    }
    const float* base = C + (size_t)row * ED + 2*lane;
#pragma unroll
    for (int k = 0; k < 4; ++k) {
      float2 c = *(const float2*)(base + (size_t)k * NV * ED);
      acc[k].x += e0 * c.x;
      acc[k].y += e1 * c.y;
    }
  }
#pragma unroll
  for (int k = 0; k < 4; ++k)
    *(float2*)(Mt + (size_t)k * BMD + (size_t)bm * ED + 2*lane) = acc[k];
}

// ---------------------------------------------------------------------------
// Kernel B: per-batch hop loop. One block (256 threads) per b.
// u0 from query; then 3 hops of scores->softmax->o->gate; writes final u.
// ---------------------------------------------------------------------------
__global__ __launch_bounds__(256) void hops_k(
    const int* __restrict__ query, const float* __restrict__ C,
    const float* __restrict__ Tw, const float* __restrict__ Tb,
    const float* __restrict__ Mt, float* __restrict__ U) {
  const int b = blockIdx.x;
  const int tid = threadIdx.x;
  const int d = tid & 127;
  const int p = tid >> 7;                        // 0/1 split
  __shared__ float u[ED];
  __shared__ float part[256];
  __shared__ float sc[NM];
  __shared__ float o[ED];

  // ---- u0 = sum_s enc[s][d] * C0[query[b][s]][d]
  {
    float accv = 0.f;
    const float ad = (float)(d + 1) - 64.5f;
    for (int s = p; s < SS; s += 2) {
      float e;
      if (s == SS - 1) e = 1.0f;
      else { float js = (float)(s + 1) - 25.5f; e = 1.0f + ad * js * 6.25e-4f; }
      int row = query[b * SS + s];
      accv += e * C[(size_t)row * ED + d];
    }
    part[tid] = accv;
  }
  __syncthreads();
  if (tid < ED) u[tid] = part[tid] + part[tid + 128];
  __syncthreads();

  for (int hop = 0; hop < 3; ++hop) {
    const float* MA = Mt + (size_t)hop * BMD + (size_t)b * NM * ED;
    const float* MC = MA + BMD;                  // table k=hop+1
    const int wave = tid >> 6, lane = tid & 63;

    // ---- scores[m] = dot(MA[m], u)
    float u_lo = u[lane], u_hi = u[lane + 64];
    for (int m = wave; m < NM; m += 4) {
      const float* r = MA + (size_t)m * ED;
      float pa = r[lane] * u_lo + r[lane + 64] * u_hi;
#pragma unroll
      for (int off = 32; off; off >>= 1) pa += __shfl_xor(pa, off);
      if (lane == 0) sc[m] = pa;
    }
    __syncthreads();

    // ---- softmax over m (max, exp, sum)
    float mx = (tid < NM) ? sc[tid] : -1e30f;
    part[tid] = mx; __syncthreads();
#pragma unroll
    for (int off = 128; off; off >>= 1) {
      if (tid < off) part[tid] = fmaxf(part[tid], part[tid + off]);
      __syncthreads();
    }
    mx = part[0];
    __syncthreads();
    float ev = 0.f;
    if (tid < NM) { ev = __expf(sc[tid] - mx); sc[tid] = ev; }
    part[tid] = ev; __syncthreads();
#pragma unroll
    for (int off = 128; off; off >>= 1) {
      if (tid < off) part[tid] += part[tid + off];
      __syncthreads();
    }
    float inv = 1.0f / part[0];
    __syncthreads();

    // ---- o[d] = sum_m prob[m] * MC[m][d]
    float oacc = 0.f;
    for (int m = p; m < NM; m += 2) oacc += sc[m] * MC[(size_t)m * ED + d];
    part[tid] = oacc; __syncthreads();
    if (tid < ED) o[tid] = (part[tid] + part[tid + 128]) * inv;
    __syncthreads();

    // ---- t = sigmoid(u @ Tw^T + Tb); u = (1-t)*u + o*t
    float tacc = 0.f;
    {
      const float* twr = Tw + (size_t)d * ED + p * 64;
      const float* ub = u + p * 64;
#pragma unroll 8
      for (int e = 0; e < 64; ++e) tacc += ub[e] * twr[e];
    }
    part[tid] = tacc; __syncthreads();
    if (tid < ED) {
      float dot = part[tid] + part[tid + 128] + Tb[tid];
      float tk = 1.0f / (1.0f + __expf(-dot));
      u[tid] = (1.0f - tk) * u[tid] + o[tid] * tk;
    }
    __syncthreads();
  }
  if (tid < ED) U[(size_t)b * ED + tid] = u[tid];
}

// ---------------------------------------------------------------------------
// Kernel C: a_hat[b][v] = sum_d U[b][d] * C3[v][d]
// Block tile: 64 b x 64 v, both operands transposed into LDS ([d][.]),
// each thread computes 4b x 4v with float4 LDS reads. 64 KB LDS.
// ---------------------------------------------------------------------------
__global__ __launch_bounds__(256) void out_mm_k(
    const float* __restrict__ U, const float* __restrict__ C3,
    float* __restrict__ out) {
  __shared__ float ut[ED * 64];   // [d][b-local]
  __shared__ float ct[ED * 64];   // [d][v-local]
  const int tid = threadIdx.x;
  const int v0 = (int)(blockIdx.x >> 1) * 64;
  const int b0 = (int)(blockIdx.x & 1) * 64;

  for (int i = tid; i < 64 * ED; i += 256) {
    int bb = i >> 7, dd = i & 127;
    ut[dd * 64 + bb] = U[(size_t)(b0 + bb) * ED + dd];
  }
  const int vcnt = min(64, NV - v0);
  for (int i = tid; i < vcnt * ED; i += 256) {
    int vv = i >> 7, dd = i & 127;
    ct[dd * 64 + vv] = C3[(size_t)(v0 + vv) * ED + dd];
  }
  __syncthreads();

  const int vb = (tid & 15) * 4;   // 16 v-groups of 4
  const int bb = (tid >> 4) * 4;   // 16 b-groups of 4
  float acc[4][4];
#pragma unroll
  for (int i = 0; i < 4; ++i)
#pragma unroll
    for (int j = 0; j < 4; ++j) acc[i][j] = 0.f;

  for (int dd = 0; dd < ED; ++dd) {
    float4 c = *(const float4*)&ct[dd * 64 + vb];
    float4 uu = *(const float4*)&ut[dd * 64 + bb];
    float uv[4] = {uu.x, uu.y, uu.z, uu.w};
    float cv[4] = {c.x, c.y, c.z, c.w};
#pragma unroll
    for (int i = 0; i < 4; ++i)
#pragma unroll
      for (int j = 0; j < 4; ++j) acc[i][j] += uv[i] * cv[j];
  }

  if (vcnt == 64) {
#pragma unroll
    for (int i = 0; i < 4; ++i) {
      float4 r = make_float4(acc[i][0], acc[i][1], acc[i][2], acc[i][3]);
      *(float4*)&out[(size_t)(b0 + bb + i) * NV + v0 + vb] = r;
    }
  } else {
    for (int i = 0; i < 4; ++i)
      for (int j = 0; j < 4; ++j)
        if (v0 + vb + j < NV)
          out[(size_t)(b0 + bb + i) * NV + v0 + vb + j] = acc[i][j];
  }
}

// ---------------------------------------------------------------------------
extern "C" void kernel_launch(void* const* d_in, const int* in_sizes, int n_in,
                              void* d_out, int out_size, void* d_ws, size_t ws_size,
                              hipStream_t stream) {
  const int*   story = (const int*)d_in[0];   // [128,200,50]
  const int*   query = (const int*)d_in[1];   // [128,50]
  const float* C     = (const float*)d_in[2]; // [4,50000,128]
  const float* Tw    = (const float*)d_in[3]; // [128,128]
  const float* Tb    = (const float*)d_in[4]; // [128]
  float* out = (float*)d_out;                 // [128,50000]

  float* wsf = (float*)d_ws;
  float* Mt  = wsf;                           // 4 * BMD floats
  float* U   = wsf + (size_t)4 * BMD;         // 128*128 floats

  hipLaunchKernelGGL(story_embed_k, dim3(NB * NM / 4), dim3(256), 0, stream,
                     story, C, Mt);
  hipLaunchKernelGGL(hops_k, dim3(NB), dim3(256), 0, stream,
                     query, C, Tw, Tb, Mt, U);
  hipLaunchKernelGGL(out_mm_k, dim3(((NV + 63) / 64) * 2), dim3(256), 0, stream,
                     U, C + (size_t)3 * NV * ED, out);
}

// Round 3
// 598.639 us; speedup vs baseline: 1.1725x; 1.1725x over previous
//
#include <hip/hip_runtime.h>
#include <hip/hip_bf16.h>
#include <cstdint>
#include <cstddef>

#define NV 50000
#define ED 128
#define SS 50
#define NB 128
#define NM 200
#define BMD (NB*NM*ED)   // 3,276,800 floats per table

// ---------------------------------------------------------------------------
// Kernel A: M_k[b][m][d] = sum_s enc[s][d] * C[k][story[b][m][s]][d], k=0..3
// One wave per (b,m). Lane covers 4 d's (float4, 16B); half-wave h handles
// s of parity h (32 lanes x 16B = one 512B row per table per half-wave).
// Cross-half combine via shfl_xor(32). 4 tables x float4 = 8 concurrent
// 16B loads per lane-pair per s2 iteration -> high MLP.
// ---------------------------------------------------------------------------
__global__ __launch_bounds__(256) void story_embed_k(
    const int* __restrict__ story, const float* __restrict__ C,
    float* __restrict__ Mt) {
  const int wave = threadIdx.x >> 6;
  const int lane = threadIdx.x & 63;
  const int bm = blockIdx.x * 4 + wave;          // < 25600
  const int* idx = story + (size_t)bm * SS;
  int myidx = (lane < SS) ? idx[lane] : 0;       // lane l holds idx[l]
  const int half = lane >> 5;                    // 0: even s, 1: odd s
  const int d0 = (lane & 31) * 4;                // 0..124
  float a0 = ((float)(d0 + 1) - 64.5f) * 6.25e-4f;
  float a1 = ((float)(d0 + 2) - 64.5f) * 6.25e-4f;
  float a2 = ((float)(d0 + 3) - 64.5f) * 6.25e-4f;
  float a3 = ((float)(d0 + 4) - 64.5f) * 6.25e-4f;
  float4 acc[4];
#pragma unroll
  for (int k = 0; k < 4; ++k) acc[k] = make_float4(0.f, 0.f, 0.f, 0.f);

#pragma unroll 5
  for (int s2 = 0; s2 < 25; ++s2) {
    const int s = 2 * s2 + half;                 // half0: 0..48, half1: 1..49
    const int row = __shfl(myidx, s);
    float e0, e1, e2, e3;
    if (s == SS - 1) { e0 = e1 = e2 = e3 = 1.0f; }
    else {
      float js = (float)(s + 1) - 25.5f;
      e0 = fmaf(a0, js, 1.0f);
      e1 = fmaf(a1, js, 1.0f);
      e2 = fmaf(a2, js, 1.0f);
      e3 = fmaf(a3, js, 1.0f);
    }
    const float* base = C + (size_t)row * ED + d0;
#pragma unroll
    for (int k = 0; k < 4; ++k) {
      float4 c = *(const float4*)(base + (size_t)k * NV * ED);
      acc[k].x = fmaf(e0, c.x, acc[k].x);
      acc[k].y = fmaf(e1, c.y, acc[k].y);
      acc[k].z = fmaf(e2, c.z, acc[k].z);
      acc[k].w = fmaf(e3, c.w, acc[k].w);
    }
  }

  // combine the two half-waves (same d0 in lane and lane^32)
#pragma unroll
  for (int k = 0; k < 4; ++k) {
    acc[k].x += __shfl_xor(acc[k].x, 32);
    acc[k].y += __shfl_xor(acc[k].y, 32);
    acc[k].z += __shfl_xor(acc[k].z, 32);
    acc[k].w += __shfl_xor(acc[k].w, 32);
  }

  // half 0 stores tables 0,1; half 1 stores tables 2,3 (32-lane 512B stores)
  float4 s0 = half ? acc[2] : acc[0];
  float4 s1 = half ? acc[3] : acc[1];
  float* outp = Mt + (size_t)half * 2 * BMD + (size_t)bm * ED + d0;
  *(float4*)outp = s0;
  *(float4*)(outp + BMD) = s1;
}

// ---------------------------------------------------------------------------
// Kernel B: per-batch hop loop. One block of 512 threads (8 waves) per b.
// ---------------------------------------------------------------------------
__global__ __launch_bounds__(512) void hops_k(
    const int* __restrict__ query, const float* __restrict__ C,
    const float* __restrict__ Tw, const float* __restrict__ Tb,
    const float* __restrict__ Mt, float* __restrict__ U) {
  const int b = blockIdx.x;
  const int tid = threadIdx.x;                   // 0..511
  const int d = tid & 127;
  const int p = tid >> 7;                        // 0..3
  const int wave = tid >> 6, lane = tid & 63;
  __shared__ float u[ED];
  __shared__ float part[512];
  __shared__ float sc[NM];
  __shared__ float o[ED];

  // ---- u0 = sum_s enc[s][d] * C0[query[b][s]][d]
  {
    float accv = 0.f;
    const float ad = ((float)(d + 1) - 64.5f) * 6.25e-4f;
    for (int s = p; s < SS; s += 4) {
      float e;
      if (s == SS - 1) e = 1.0f;
      else { float js = (float)(s + 1) - 25.5f; e = fmaf(ad, js, 1.0f); }
      int row = query[b * SS + s];
      accv = fmaf(e, C[(size_t)row * ED + d], accv);
    }
    part[tid] = accv;
  }
  __syncthreads();
  if (tid < ED)
    u[tid] = part[tid] + part[tid + 128] + part[tid + 256] + part[tid + 384];
  __syncthreads();

  for (int hop = 0; hop < 3; ++hop) {
    const float* MA = Mt + (size_t)hop * BMD + (size_t)b * NM * ED;
    const float* MC = MA + BMD;                  // table k = hop+1

    // ---- scores[m] = dot(MA[m], u); 8 waves, 2 m in flight per wave
    float u0v = u[2 * lane], u1v = u[2 * lane + 1];
    for (int m = wave; m < NM; m += 16) {
      const int m2 = m + 8;
      const bool has2 = (m2 < NM);
      float2 r0 = *(const float2*)(MA + (size_t)m * ED + 2 * lane);
      float pa = r0.x * u0v + r0.y * u1v;
      float pb = 0.f;
      if (has2) {
        float2 r1 = *(const float2*)(MA + (size_t)m2 * ED + 2 * lane);
        pb = r1.x * u0v + r1.y * u1v;
      }
#pragma unroll
      for (int off = 32; off; off >>= 1) {
        pa += __shfl_xor(pa, off);
        pb += __shfl_xor(pb, off);
      }
      if (lane == 0) {
        sc[m] = pa;
        if (has2) sc[m2] = pb;
      }
    }
    __syncthreads();

    // ---- softmax over m
    float mx = (tid < NM) ? sc[tid] : -1e30f;
    part[tid] = mx; __syncthreads();
#pragma unroll
    for (int off = 256; off; off >>= 1) {
      if (tid < off) part[tid] = fmaxf(part[tid], part[tid + off]);
      __syncthreads();
    }
    mx = part[0];
    __syncthreads();
    float ev = 0.f;
    if (tid < NM) { ev = __expf(sc[tid] - mx); sc[tid] = ev; }
    part[tid] = ev; __syncthreads();
#pragma unroll
    for (int off = 256; off; off >>= 1) {
      if (tid < off) part[tid] += part[tid + off];
      __syncthreads();
    }
    float inv = 1.0f / part[0];
    __syncthreads();

    // ---- o[d] = (sum_m sc[m] * MC[m][d]) * inv
    float oacc = 0.f;
    for (int m = p; m < NM; m += 4)
      oacc = fmaf(sc[m], MC[(size_t)m * ED + d], oacc);
    part[tid] = oacc; __syncthreads();
    if (tid < ED)
      o[tid] = (part[tid] + part[tid + 128] + part[tid + 256] + part[tid + 384])
               * inv;
    __syncthreads();

    // ---- t = sigmoid(u @ Tw^T + Tb); u = (1-t)*u + o*t
    float tacc = 0.f;
    {
      const float* twr = Tw + (size_t)d * ED + p * 32;
      const float* ub = u + p * 32;
#pragma unroll 8
      for (int e = 0; e < 32; ++e) tacc = fmaf(ub[e], twr[e], tacc);
    }
    part[tid] = tacc; __syncthreads();
    if (tid < ED) {
      float dot = part[tid] + part[tid + 128] + part[tid + 256] + part[tid + 384]
                  + Tb[tid];
      float tk = 1.0f / (1.0f + __expf(-dot));
      u[tid] = (1.0f - tk) * u[tid] + o[tid] * tk;
    }
    __syncthreads();
  }
  if (tid < ED) U[(size_t)b * ED + tid] = u[tid];
}

// ---------------------------------------------------------------------------
// Kernel C: a_hat[b][v] = sum_d U[b][d] * C3[v][d]
// 64b x 64v tile, operands transposed into LDS (stride 68 breaks the
// 64-way write conflict while keeping float4 alignment).
// ---------------------------------------------------------------------------
#define LSTR 68
__global__ __launch_bounds__(256) void out_mm_k(
    const float* __restrict__ U, const float* __restrict__ C3,
    float* __restrict__ out) {
  __shared__ float ut[ED * LSTR];   // [d][b-local]
  __shared__ float ct[ED * LSTR];   // [d][v-local]
  const int tid = threadIdx.x;
  const int v0 = (int)(blockIdx.x >> 1) * 64;
  const int b0 = (int)(blockIdx.x & 1) * 64;

  for (int i = tid; i < 64 * ED; i += 256) {
    int bb = i >> 7, dd = i & 127;
    ut[dd * LSTR + bb] = U[(size_t)(b0 + bb) * ED + dd];
  }
  const int vcnt = min(64, NV - v0);
  for (int i = tid; i < vcnt * ED; i += 256) {
    int vv = i >> 7, dd = i & 127;
    ct[dd * LSTR + vv] = C3[(size_t)(v0 + vv) * ED + dd];
  }
  __syncthreads();

  const int vb = (tid & 15) * 4;
  const int bb = (tid >> 4) * 4;
  float acc[4][4];
#pragma unroll
  for (int i = 0; i < 4; ++i)
#pragma unroll
    for (int j = 0; j < 4; ++j) acc[i][j] = 0.f;

  for (int dd = 0; dd < ED; ++dd) {
    float4 c = *(const float4*)&ct[dd * LSTR + vb];
    float4 uu = *(const float4*)&ut[dd * LSTR + bb];
    float uv[4] = {uu.x, uu.y, uu.z, uu.w};
    float cv[4] = {c.x, c.y, c.z, c.w};
#pragma unroll
    for (int i = 0; i < 4; ++i)
#pragma unroll
      for (int j = 0; j < 4; ++j) acc[i][j] += uv[i] * cv[j];
  }

  if (vcnt == 64) {
#pragma unroll
    for (int i = 0; i < 4; ++i) {
      float4 r = make_float4(acc[i][0], acc[i][1], acc[i][2], acc[i][3]);
      *(float4*)&out[(size_t)(b0 + bb + i) * NV + v0 + vb] = r;
    }
  } else {
    for (int i = 0; i < 4; ++i)
      for (int j = 0; j < 4; ++j)
        if (v0 + vb + j < NV)
          out[(size_t)(b0 + bb + i) * NV + v0 + vb + j] = acc[i][j];
  }
}

// ---------------------------------------------------------------------------
extern "C" void kernel_launch(void* const* d_in, const int* in_sizes, int n_in,
                              void* d_out, int out_size, void* d_ws, size_t ws_size,
                              hipStream_t stream) {
  const int*   story = (const int*)d_in[0];   // [128,200,50]
  const int*   query = (const int*)d_in[1];   // [128,50]
  const float* C     = (const float*)d_in[2]; // [4,50000,128]
  const float* Tw    = (const float*)d_in[3]; // [128,128]
  const float* Tb    = (const float*)d_in[4]; // [128]
  float* out = (float*)d_out;                 // [128,50000]

  float* wsf = (float*)d_ws;
  float* Mt  = wsf;                           // 4 * BMD floats
  float* U   = wsf + (size_t)4 * BMD;         // 128*128 floats

  hipLaunchKernelGGL(story_embed_k, dim3(NB * NM / 4), dim3(256), 0, stream,
                     story, C, Mt);
  hipLaunchKernelGGL(hops_k, dim3(NB), dim3(512), 0, stream,
                     query, C, Tw, Tb, Mt, U);
  hipLaunchKernelGGL(out_mm_k, dim3(((NV + 63) / 64) * 2), dim3(256), 0, stream,
                     U, C + (size_t)3 * NV * ED, out);
}

// Round 4
// 453.635 us; speedup vs baseline: 1.5473x; 1.3196x over previous
//
#include <hip/hip_runtime.h>
#include <cstdint>
#include <cstddef>

#define NV 50000
#define ED 128
#define SS 50
#define NB 128
#define NM 200
#define BMD (NB*NM*ED)   // 3,276,800 floats per table
#define NCH 32
#define CHD 1563         // ceil(50000/32); chunks 0..31, last has 1547 rows

// ---------------------------------------------------------------------------
// Kernel A: vocab-chunked gather-reduce.
// M_k[bm][d] = sum_s enc[s][d] * C[k][story[bm][s]][d], k=0..3.
// Grid = 1600 blocks x 256 thr (ALL co-resident -> one generation). Block owns
// 16 bm rows; wave owns 4 (tokens + 4x4 float2 accumulators in registers).
// Chunk sweep c=0..31: per wave/row, ballot-select tokens with idx/CHD == c,
// gather only those. All co-resident waves touch the same 3.2 MB table slice
// (4 tables x 1563 rows x 512B) -> per-XCD-L2-resident; misses are sequential.
// ---------------------------------------------------------------------------
__global__ __launch_bounds__(256) void story_embed_k(
    const int* __restrict__ story, const float* __restrict__ C,
    float* __restrict__ Mt) {
  const int wave = threadIdx.x >> 6;
  const int lane = threadIdx.x & 63;
  const int bm0 = blockIdx.x * 16;
  const int sl = (lane < SS) ? lane : (SS - 1);   // avoid OOB read past row

  int idxg[4], cidg[4];
#pragma unroll
  for (int gg = 0; gg < 4; ++gg) {
    const int bm = bm0 + wave + 4 * gg;
    idxg[gg] = story[(size_t)bm * SS + sl];
    cidg[gg] = (lane < SS) ? (idxg[gg] / CHD) : -1;
  }
  const float a0 = ((float)(2*lane + 1) - 64.5f) * 6.25e-4f;
  const float a1 = ((float)(2*lane + 2) - 64.5f) * 6.25e-4f;
  float2 acc[4][4];
#pragma unroll
  for (int gg = 0; gg < 4; ++gg)
#pragma unroll
    for (int k = 0; k < 4; ++k) acc[gg][k] = make_float2(0.f, 0.f);

  for (int c = 0; c < NCH; ++c) {
#pragma unroll
    for (int gg = 0; gg < 4; ++gg) {
      unsigned long long mask = __ballot(cidg[gg] == c);
      while (mask) {
        const int s = __builtin_ctzll(mask);
        mask &= mask - 1;
        const int row = __shfl(idxg[gg], s);
        float e0, e1;
        if (s == SS - 1) { e0 = 1.0f; e1 = 1.0f; }
        else {
          float js = (float)(s + 1) - 25.5f;
          e0 = fmaf(a0, js, 1.0f);
          e1 = fmaf(a1, js, 1.0f);
        }
        const float* base = C + (size_t)row * ED + 2 * lane;
#pragma unroll
        for (int k = 0; k < 4; ++k) {
          float2 cv = *(const float2*)(base + (size_t)k * NV * ED);
          acc[gg][k].x = fmaf(e0, cv.x, acc[gg][k].x);
          acc[gg][k].y = fmaf(e1, cv.y, acc[gg][k].y);
        }
      }
    }
    __syncthreads();   // keep the block's waves sweeping chunks in lockstep
  }

#pragma unroll
  for (int gg = 0; gg < 4; ++gg) {
    const int bm = bm0 + wave + 4 * gg;
#pragma unroll
    for (int k = 0; k < 4; ++k)
      *(float2*)(Mt + (size_t)k * BMD + (size_t)bm * ED + 2 * lane) = acc[gg][k];
  }
}

// ---------------------------------------------------------------------------
// Kernel B: per-batch hop loop, 512 threads/block, 1 block per b.
// Active table staged into a 100 KB LDS tile with float4 max-MLP loads;
// score + o phases read LDS. Softmax uses wave shfl reduce (few barriers).
// ---------------------------------------------------------------------------
__global__ __launch_bounds__(512) void hops_k(
    const int* __restrict__ query, const float* __restrict__ C,
    const float* __restrict__ Tw, const float* __restrict__ Tb,
    const float* __restrict__ Mt, float* __restrict__ U) {
  const int b = blockIdx.x;
  const int tid = threadIdx.x;                   // 0..511
  const int d = tid & 127;
  const int p = tid >> 7;                        // 0..3
  const int wave = tid >> 6, lane = tid & 63;
  __shared__ float tile[NM * ED];                // 102,400 B
  __shared__ float u[ED];
  __shared__ float part[512];
  __shared__ float sc[NM];
  __shared__ float o[ED];

  // ---- u0 = sum_s enc[s][d] * C0[query[b][s]][d]
  {
    float accv = 0.f;
    const float ad = ((float)(d + 1) - 64.5f) * 6.25e-4f;
    for (int s = p; s < SS; s += 4) {
      float e;
      if (s == SS - 1) e = 1.0f;
      else { float js = (float)(s + 1) - 25.5f; e = fmaf(ad, js, 1.0f); }
      int row = query[b * SS + s];
      accv = fmaf(e, C[(size_t)row * ED + d], accv);
    }
    part[tid] = accv;
  }
  __syncthreads();
  if (tid < ED)
    u[tid] = part[tid] + part[tid + 128] + part[tid + 256] + part[tid + 384];
  __syncthreads();

  for (int hop = 0; hop < 3; ++hop) {
    const float* MA = Mt + (size_t)hop * BMD + (size_t)b * NM * ED;
    const float* MC = MA + BMD;                  // table k = hop+1

    // ---- stage MA -> LDS tile (6400 float4, all-thread MLP)
    {
      float4* t4 = (float4*)tile;
      const float4* s4 = (const float4*)MA;
      for (int i = tid; i < NM * ED / 4; i += 512) t4[i] = s4[i];
    }
    __syncthreads();

    // ---- scores[m] = dot(tile[m], u); wave per m, 2 in flight
    {
      float u0v = u[2 * lane], u1v = u[2 * lane + 1];
      for (int m = wave; m < NM; m += 16) {
        const int m2 = m + 8;
        const bool has2 = (m2 < NM);
        float2 r0 = *(const float2*)&tile[m * ED + 2 * lane];
        float pa = r0.x * u0v + r0.y * u1v;
        float pb = 0.f;
        if (has2) {
          float2 r1 = *(const float2*)&tile[m2 * ED + 2 * lane];
          pb = r1.x * u0v + r1.y * u1v;
        }
#pragma unroll
        for (int off = 32; off; off >>= 1) {
          pa += __shfl_xor(pa, off);
          pb += __shfl_xor(pb, off);
        }
        if (lane == 0) {
          sc[m] = pa;
          if (has2) sc[m2] = pb;
        }
      }
    }
    __syncthreads();

    // ---- softmax: wave shfl reductions, part[0..7]=max, part[8..15]=sum
    float v = (tid < NM) ? sc[tid] : -1e30f;
    {
      float t = v;
#pragma unroll
      for (int off = 32; off; off >>= 1) t = fmaxf(t, __shfl_xor(t, off));
      if (lane == 0) part[wave] = t;
    }
    __syncthreads();
    float mx = part[0];
#pragma unroll
    for (int w = 1; w < 8; ++w) mx = fmaxf(mx, part[w]);
    float ev = 0.f;
    if (tid < NM) { ev = __expf(v - mx); sc[tid] = ev; }
    {
      float t = ev;
#pragma unroll
      for (int off = 32; off; off >>= 1) t += __shfl_xor(t, off);
      if (lane == 0) part[8 + wave] = t;
    }
    __syncthreads();
    float tot = part[8];
#pragma unroll
    for (int w = 9; w < 16; ++w) tot += part[w];
    const float inv = 1.0f / tot;
    __syncthreads();   // sc writes visible; tile reads all complete

    // ---- stage MC -> LDS tile (overwrite)
    {
      float4* t4 = (float4*)tile;
      const float4* s4 = (const float4*)MC;
      for (int i = tid; i < NM * ED / 4; i += 512) t4[i] = s4[i];
    }
    __syncthreads();

    // ---- o[d] = (sum_m sc[m] * tile[m][d]) * inv
    {
      float oacc = 0.f;
      for (int m = p; m < NM; m += 4)
        oacc = fmaf(sc[m], tile[m * ED + d], oacc);
      part[tid] = oacc;
    }
    __syncthreads();
    if (tid < ED)
      o[tid] = (part[tid] + part[tid + 128] + part[tid + 256] + part[tid + 384])
               * inv;
    __syncthreads();

    // ---- t = sigmoid(u @ Tw^T + Tb); u = (1-t)*u + o*t
    {
      float tacc = 0.f;
      const float* twr = Tw + (size_t)d * ED + p * 32;
      const float* ub = u + p * 32;
#pragma unroll 8
      for (int e = 0; e < 32; ++e) tacc = fmaf(ub[e], twr[e], tacc);
      part[tid] = tacc;
    }
    __syncthreads();
    if (tid < ED) {
      float dot = part[tid] + part[tid + 128] + part[tid + 256] + part[tid + 384]
                  + Tb[tid];
      float tk = 1.0f / (1.0f + __expf(-dot));
      u[tid] = (1.0f - tk) * u[tid] + o[tid] * tk;
    }
    __syncthreads();
  }
  if (tid < ED) U[(size_t)b * ED + tid] = u[tid];
}

// ---------------------------------------------------------------------------
// Kernel C: a_hat[b][v] = sum_d U[b][d] * C3[v][d]  (unchanged from r3)
// ---------------------------------------------------------------------------
#define LSTR 68
__global__ __launch_bounds__(256) void out_mm_k(
    const float* __restrict__ U, const float* __restrict__ C3,
    float* __restrict__ out) {
  __shared__ float ut[ED * LSTR];
  __shared__ float ct[ED * LSTR];
  const int tid = threadIdx.x;
  const int v0 = (int)(blockIdx.x >> 1) * 64;
  const int b0 = (int)(blockIdx.x & 1) * 64;

  for (int i = tid; i < 64 * ED; i += 256) {
    int bb = i >> 7, dd = i & 127;
    ut[dd * LSTR + bb] = U[(size_t)(b0 + bb) * ED + dd];
  }
  const int vcnt = min(64, NV - v0);
  for (int i = tid; i < vcnt * ED; i += 256) {
    int vv = i >> 7, dd = i & 127;
    ct[dd * LSTR + vv] = C3[(size_t)(v0 + vv) * ED + dd];
  }
  __syncthreads();

  const int vb = (tid & 15) * 4;
  const int bb = (tid >> 4) * 4;
  float acc[4][4];
#pragma unroll
  for (int i = 0; i < 4; ++i)
#pragma unroll
    for (int j = 0; j < 4; ++j) acc[i][j] = 0.f;

  for (int dd = 0; dd < ED; ++dd) {
    float4 c = *(const float4*)&ct[dd * LSTR + vb];
    float4 uu = *(const float4*)&ut[dd * LSTR + bb];
    float uv[4] = {uu.x, uu.y, uu.z, uu.w};
    float cv[4] = {c.x, c.y, c.z, c.w};
#pragma unroll
    for (int i = 0; i < 4; ++i)
#pragma unroll
      for (int j = 0; j < 4; ++j) acc[i][j] += uv[i] * cv[j];
  }

  if (vcnt == 64) {
#pragma unroll
    for (int i = 0; i < 4; ++i) {
      float4 r = make_float4(acc[i][0], acc[i][1], acc[i][2], acc[i][3]);
      *(float4*)&out[(size_t)(b0 + bb + i) * NV + v0 + vb] = r;
    }
  } else {
    for (int i = 0; i < 4; ++i)
      for (int j = 0; j < 4; ++j)
        if (v0 + vb + j < NV)
          out[(size_t)(b0 + bb + i) * NV + v0 + vb + j] = acc[i][j];
  }
}

// ---------------------------------------------------------------------------
extern "C" void kernel_launch(void* const* d_in, const int* in_sizes, int n_in,
                              void* d_out, int out_size, void* d_ws, size_t ws_size,
                              hipStream_t stream) {
  const int*   story = (const int*)d_in[0];   // [128,200,50]
  const int*   query = (const int*)d_in[1];   // [128,50]
  const float* C     = (const float*)d_in[2]; // [4,50000,128]
  const float* Tw    = (const float*)d_in[3]; // [128,128]
  const float* Tb    = (const float*)d_in[4]; // [128]
  float* out = (float*)d_out;                 // [128,50000]

  float* wsf = (float*)d_ws;
  float* Mt  = wsf;                           // 4 * BMD floats
  float* U   = wsf + (size_t)4 * BMD;         // 128*128 floats

  hipLaunchKernelGGL(story_embed_k, dim3(NB * NM / 16), dim3(256), 0, stream,
                     story, C, Mt);
  hipLaunchKernelGGL(hops_k, dim3(NB), dim3(512), 0, stream,
                     query, C, Tw, Tb, Mt, U);
  hipLaunchKernelGGL(out_mm_k, dim3(((NV + 63) / 64) * 2), dim3(256), 0, stream,
                     U, C + (size_t)3 * NV * ED, out);
}

// Round 6
// 445.331 us; speedup vs baseline: 1.5761x; 1.0186x over previous
//
#include <hip/hip_runtime.h>
#include <cstdint>
#include <cstddef>

#define NV 50000
#define ED 128
#define SS 50
#define NB 128
#define NM 200
#define BMD (NB*NM*ED)   // 3,276,800 floats per table
#define NCH 32
#define CHD 1563         // ceil(50000/32)

// ---------------------------------------------------------------------------
// Kernel A: vocab-chunked gather-reduce (unchanged — ~92% of the ~3.4 TB/s
// miss-path roofline with FETCH at the 8-XCD compulsory floor).
// ---------------------------------------------------------------------------
__global__ __launch_bounds__(256) void story_embed_k(
    const int* __restrict__ story, const float* __restrict__ C,
    float* __restrict__ Mt) {
  const int wave = threadIdx.x >> 6;
  const int lane = threadIdx.x & 63;
  const int bm0 = blockIdx.x * 16;
  const int sl = (lane < SS) ? lane : (SS - 1);

  int idxg[4], cidg[4];
#pragma unroll
  for (int gg = 0; gg < 4; ++gg) {
    const int bm = bm0 + wave + 4 * gg;
    idxg[gg] = story[(size_t)bm * SS + sl];
    cidg[gg] = (lane < SS) ? (idxg[gg] / CHD) : -1;
  }
  const float a0 = ((float)(2*lane + 1) - 64.5f) * 6.25e-4f;
  const float a1 = ((float)(2*lane + 2) - 64.5f) * 6.25e-4f;
  float2 acc[4][4];
#pragma unroll
  for (int gg = 0; gg < 4; ++gg)
#pragma unroll
    for (int k = 0; k < 4; ++k) acc[gg][k] = make_float2(0.f, 0.f);

  for (int c = 0; c < NCH; ++c) {
#pragma unroll
    for (int gg = 0; gg < 4; ++gg) {
      unsigned long long mask = __ballot(cidg[gg] == c);
      while (mask) {
        const int s = __builtin_ctzll(mask);
        mask &= mask - 1;
        const int row = __shfl(idxg[gg], s);
        float e0, e1;
        if (s == SS - 1) { e0 = 1.0f; e1 = 1.0f; }
        else {
          float js = (float)(s + 1) - 25.5f;
          e0 = fmaf(a0, js, 1.0f);
          e1 = fmaf(a1, js, 1.0f);
        }
        const float* base = C + (size_t)row * ED + 2 * lane;
#pragma unroll
        for (int k = 0; k < 4; ++k) {
          float2 cv = *(const float2*)(base + (size_t)k * NV * ED);
          acc[gg][k].x = fmaf(e0, cv.x, acc[gg][k].x);
          acc[gg][k].y = fmaf(e1, cv.y, acc[gg][k].y);
        }
      }
    }
    __syncthreads();
  }

#pragma unroll
  for (int gg = 0; gg < 4; ++gg) {
    const int bm = bm0 + wave + 4 * gg;
#pragma unroll
    for (int k = 0; k < 4; ++k)
      *(float2*)(Mt + (size_t)k * BMD + (size_t)bm * ED + 2 * lane) = acc[gg][k];
  }
}

// ---------------------------------------------------------------------------
// Kernel B: per-batch hop loop, 512 thr/block, 1 block per b.
// Global->LDS/reg staging two-phase register-buffered (kills per-iteration
// vmcnt(0) serialization). BUGFIX vs r5: o-loop covers all NM=200 memories
// (50 iterations of stride 4), not 13.
// ---------------------------------------------------------------------------
__global__ __launch_bounds__(512) void hops_k(
    const int* __restrict__ query, const float* __restrict__ C,
    const float* __restrict__ Tw, const float* __restrict__ Tb,
    const float* __restrict__ Mt, float* __restrict__ U) {
  const int b = blockIdx.x;
  const int tid = threadIdx.x;                   // 0..511
  const int d = tid & 127;
  const int p = tid >> 7;                        // 0..3
  const int wave = tid >> 6, lane = tid & 63;
  __shared__ float tile[NM * ED];                // 102,400 B
  __shared__ float u[ED];
  __shared__ float part[512];
  __shared__ float sc[NM];
  __shared__ float o[ED];

  // ---- u0 = sum_s enc[s][d] * C0[query[b][s]][d] (reg-buffered, MLP 13)
  {
    const float ad = ((float)(d + 1) - 64.5f) * 6.25e-4f;
    int rows[13];
#pragma unroll
    for (int j = 0; j < 13; ++j) {
      int s = p + 4 * j;
      rows[j] = query[b * SS + (s < SS ? s : 0)];
    }
    float cv[13];
#pragma unroll
    for (int j = 0; j < 13; ++j)
      cv[j] = C[(size_t)rows[j] * ED + d];
    float accv = 0.f;
#pragma unroll
    for (int j = 0; j < 13; ++j) {
      int s = p + 4 * j;
      float e;
      if (s >= SS) e = 0.f;
      else if (s == SS - 1) e = 1.0f;
      else e = fmaf(ad, (float)(s + 1) - 25.5f, 1.0f);
      accv = fmaf(e, cv[j], accv);
    }
    part[tid] = accv;
  }
  __syncthreads();
  if (tid < ED)
    u[tid] = part[tid] + part[tid + 128] + part[tid + 256] + part[tid + 384];
  __syncthreads();

  for (int hop = 0; hop < 3; ++hop) {
    const float* MA = Mt + (size_t)hop * BMD + (size_t)b * NM * ED;
    const float* MC = MA + BMD;                  // table k = hop+1

    // ---- stage MA -> LDS (6400 float4; 13 reg-buffered per thread)
    {
      float4* t4 = (float4*)tile;
      const float4* s4 = (const float4*)MA;
      float4 st[13];
#pragma unroll
      for (int j = 0; j < 13; ++j) {
        int i = tid + 512 * j;
        st[j] = (i < NM * ED / 4) ? s4[i] : make_float4(0.f, 0.f, 0.f, 0.f);
      }
#pragma unroll
      for (int j = 0; j < 13; ++j) {
        int i = tid + 512 * j;
        if (i < NM * ED / 4) t4[i] = st[j];
      }
    }
    __syncthreads();

    // ---- scores[m] = dot(tile[m], u)
    {
      float u0v = u[2 * lane], u1v = u[2 * lane + 1];
      for (int m = wave; m < NM; m += 16) {
        const int m2 = m + 8;
        const bool has2 = (m2 < NM);
        float2 r0 = *(const float2*)&tile[m * ED + 2 * lane];
        float pa = r0.x * u0v + r0.y * u1v;
        float pb = 0.f;
        if (has2) {
          float2 r1 = *(const float2*)&tile[m2 * ED + 2 * lane];
          pb = r1.x * u0v + r1.y * u1v;
        }
#pragma unroll
        for (int off = 32; off; off >>= 1) {
          pa += __shfl_xor(pa, off);
          pb += __shfl_xor(pb, off);
        }
        if (lane == 0) {
          sc[m] = pa;
          if (has2) sc[m2] = pb;
        }
      }
    }
    __syncthreads();

    // ---- softmax (wave shfl reductions)
    float v = (tid < NM) ? sc[tid] : -1e30f;
    {
      float t = v;
#pragma unroll
      for (int off = 32; off; off >>= 1) t = fmaxf(t, __shfl_xor(t, off));
      if (lane == 0) part[wave] = t;
    }
    __syncthreads();
    float mx = part[0];
#pragma unroll
    for (int w = 1; w < 8; ++w) mx = fmaxf(mx, part[w]);
    float ev = 0.f;
    if (tid < NM) { ev = __expf(v - mx); sc[tid] = ev; }
    {
      float t = ev;
#pragma unroll
      for (int off = 32; off; off >>= 1) t += __shfl_xor(t, off);
      if (lane == 0) part[8 + wave] = t;
    }
    __syncthreads();
    float tot = part[8];
#pragma unroll
    for (int w = 9; w < 16; ++w) tot += part[w];
    const float inv = 1.0f / tot;
    __syncthreads();

    // ---- stage MC -> LDS (reg-buffered)
    {
      float4* t4 = (float4*)tile;
      const float4* s4 = (const float4*)MC;
      float4 st[13];
#pragma unroll
      for (int j = 0; j < 13; ++j) {
        int i = tid + 512 * j;
        st[j] = (i < NM * ED / 4) ? s4[i] : make_float4(0.f, 0.f, 0.f, 0.f);
      }
#pragma unroll
      for (int j = 0; j < 13; ++j) {
        int i = tid + 512 * j;
        if (i < NM * ED / 4) t4[i] = st[j];
      }
    }
    __syncthreads();

    // ---- o[d] = (sum_m sc[m] * tile[m][d]) * inv
    // NM=200, stride 4 -> exactly 50 iterations (BUGFIX: was 13)
    {
      float oacc = 0.f;
#pragma unroll 10
      for (int j = 0; j < 50; ++j) {
        int m = p + 4 * j;
        oacc = fmaf(sc[m], tile[m * ED + d], oacc);
      }
      part[tid] = oacc;
    }
    __syncthreads();
    if (tid < ED)
      o[tid] = (part[tid] + part[tid + 128] + part[tid + 256] + part[tid + 384])
               * inv;
    __syncthreads();

    // ---- t = sigmoid(u @ Tw^T + Tb); u = (1-t)*u + o*t  (float4 MLP on Tw)
    {
      const float4* twr = (const float4*)(Tw + (size_t)d * ED + p * 32);
      float4 tw4[8];
#pragma unroll
      for (int j = 0; j < 8; ++j) tw4[j] = twr[j];
      float tacc = 0.f;
#pragma unroll
      for (int j = 0; j < 8; ++j) {
        tacc = fmaf(u[p * 32 + 4 * j + 0], tw4[j].x, tacc);
        tacc = fmaf(u[p * 32 + 4 * j + 1], tw4[j].y, tacc);
        tacc = fmaf(u[p * 32 + 4 * j + 2], tw4[j].z, tacc);
        tacc = fmaf(u[p * 32 + 4 * j + 3], tw4[j].w, tacc);
      }
      part[tid] = tacc;
    }
    __syncthreads();
    if (tid < ED) {
      float dot = part[tid] + part[tid + 128] + part[tid + 256] + part[tid + 384]
                  + Tb[tid];
      float tk = 1.0f / (1.0f + __expf(-dot));
      u[tid] = (1.0f - tk) * u[tid] + o[tid] * tk;
    }
    __syncthreads();
  }
  if (tid < ED) U[(size_t)b * ED + tid] = u[tid];
}

// ---------------------------------------------------------------------------
// Kernel C: a_hat[b][v] = sum_d U[b][d] * C3[v][d]
// 782 blocks: each block does ALL 128 b x 64 v (C3 read ONCE).
// ut = U un-transposed [b][129]; ct transposed [d][68]. Two-phase
// reg-buffered staging (MLP 16). Thread computes 4b x 8v.
// ---------------------------------------------------------------------------
__global__ __launch_bounds__(256) void out_mm_k(
    const float* __restrict__ U, const float* __restrict__ C3,
    float* __restrict__ out) {
  __shared__ float ut[NB * 129];    // 66,048 B
  __shared__ float ct[ED * 68];     // 34,816 B
  const int tid = threadIdx.x;
  const int v0 = blockIdx.x * 64;
  const int vcnt = min(64, NV - v0);

  // stage U (16384 floats, 64/thread, 4 batches of 16 reg-buffered)
#pragma unroll
  for (int bt = 0; bt < 4; ++bt) {
    float tmp[16];
#pragma unroll
    for (int j = 0; j < 16; ++j)
      tmp[j] = U[tid + 256 * (bt * 16 + j)];
#pragma unroll
    for (int j = 0; j < 16; ++j) {
      int i = tid + 256 * (bt * 16 + j);
      ut[(i >> 7) * 129 + (i & 127)] = tmp[j];
    }
  }
  // stage C3 tile transposed (vcnt*128 floats, 2 batches of 16)
#pragma unroll
  for (int bt = 0; bt < 2; ++bt) {
    float tmp[16];
#pragma unroll
    for (int j = 0; j < 16; ++j) {
      int i = tid + 256 * (bt * 16 + j);
      tmp[j] = (i < vcnt * ED) ? C3[(size_t)v0 * ED + i] : 0.f;
    }
#pragma unroll
    for (int j = 0; j < 16; ++j) {
      int i = tid + 256 * (bt * 16 + j);
      if (i < vcnt * ED) ct[(i & 127) * 68 + (i >> 7)] = tmp[j];
    }
  }
  __syncthreads();

  const int vb = (tid & 7) * 8;     // 8 v-groups of 8
  const int bb = (tid >> 3) * 4;    // 32 b-groups of 4
  float acc[4][8];
#pragma unroll
  for (int i = 0; i < 4; ++i)
#pragma unroll
    for (int j = 0; j < 8; ++j) acc[i][j] = 0.f;

  for (int dd = 0; dd < ED; ++dd) {
    float4 c0 = *(const float4*)&ct[dd * 68 + vb];
    float4 c1 = *(const float4*)&ct[dd * 68 + vb + 4];
    float cv[8] = {c0.x, c0.y, c0.z, c0.w, c1.x, c1.y, c1.z, c1.w};
    float ub[4];
#pragma unroll
    for (int i = 0; i < 4; ++i) ub[i] = ut[(bb + i) * 129 + dd];
#pragma unroll
    for (int i = 0; i < 4; ++i)
#pragma unroll
      for (int j = 0; j < 8; ++j) acc[i][j] = fmaf(ub[i], cv[j], acc[i][j]);
  }

  if (vcnt == 64) {
#pragma unroll
    for (int i = 0; i < 4; ++i) {
      float4 r0 = make_float4(acc[i][0], acc[i][1], acc[i][2], acc[i][3]);
      float4 r1 = make_float4(acc[i][4], acc[i][5], acc[i][6], acc[i][7]);
      float* op = &out[(size_t)(bb + i) * NV + v0 + vb];
      *(float4*)op = r0;
      *(float4*)(op + 4) = r1;
    }
  } else {
#pragma unroll
    for (int i = 0; i < 4; ++i)
      for (int j = 0; j < 8; ++j)
        if (v0 + vb + j < NV)
          out[(size_t)(bb + i) * NV + v0 + vb + j] = acc[i][j];
  }
}

// ---------------------------------------------------------------------------
extern "C" void kernel_launch(void* const* d_in, const int* in_sizes, int n_in,
                              void* d_out, int out_size, void* d_ws, size_t ws_size,
                              hipStream_t stream) {
  const int*   story = (const int*)d_in[0];   // [128,200,50]
  const int*   query = (const int*)d_in[1];   // [128,50]
  const float* C     = (const float*)d_in[2]; // [4,50000,128]
  const float* Tw    = (const float*)d_in[3]; // [128,128]
  const float* Tb    = (const float*)d_in[4]; // [128]
  float* out = (float*)d_out;                 // [128,50000]

  float* wsf = (float*)d_ws;
  float* Mt  = wsf;                           // 4 * BMD floats
  float* U   = wsf + (size_t)4 * BMD;         // 128*128 floats

  hipLaunchKernelGGL(story_embed_k, dim3(NB * NM / 16), dim3(256), 0, stream,
                     story, C, Mt);
  hipLaunchKernelGGL(hops_k, dim3(NB), dim3(512), 0, stream,
                     query, C, Tw, Tb, Mt, U);
  hipLaunchKernelGGL(out_mm_k, dim3((NV + 63) / 64), dim3(256), 0, stream,
                     U, C + (size_t)3 * NV * ED, out);
}

// Round 7
// 440.002 us; speedup vs baseline: 1.5952x; 1.0121x over previous
//
#include <hip/hip_runtime.h>
#include <cstdint>
#include <cstddef>

#define NV 50000
#define ED 128
#define SS 50
#define NB 128
#define NM 200
#define BMD (NB*NM*ED)   // 3,276,800 floats per table
#define NCH 32
#define CHD 1563         // ceil(50000/32)

// ---------------------------------------------------------------------------
// Kernel A: vocab-chunked gather-reduce (unchanged — ~92% of the ~3.4 TB/s
// miss-path roofline with FETCH at the 8-XCD compulsory floor).
// ---------------------------------------------------------------------------
__global__ __launch_bounds__(256) void story_embed_k(
    const int* __restrict__ story, const float* __restrict__ C,
    float* __restrict__ Mt) {
  const int wave = threadIdx.x >> 6;
  const int lane = threadIdx.x & 63;
  const int bm0 = blockIdx.x * 16;
  const int sl = (lane < SS) ? lane : (SS - 1);

  int idxg[4], cidg[4];
#pragma unroll
  for (int gg = 0; gg < 4; ++gg) {
    const int bm = bm0 + wave + 4 * gg;
    idxg[gg] = story[(size_t)bm * SS + sl];
    cidg[gg] = (lane < SS) ? (idxg[gg] / CHD) : -1;
  }
  const float a0 = ((float)(2*lane + 1) - 64.5f) * 6.25e-4f;
  const float a1 = ((float)(2*lane + 2) - 64.5f) * 6.25e-4f;
  float2 acc[4][4];
#pragma unroll
  for (int gg = 0; gg < 4; ++gg)
#pragma unroll
    for (int k = 0; k < 4; ++k) acc[gg][k] = make_float2(0.f, 0.f);

  for (int c = 0; c < NCH; ++c) {
#pragma unroll
    for (int gg = 0; gg < 4; ++gg) {
      unsigned long long mask = __ballot(cidg[gg] == c);
      while (mask) {
        const int s = __builtin_ctzll(mask);
        mask &= mask - 1;
        const int row = __shfl(idxg[gg], s);
        float e0, e1;
        if (s == SS - 1) { e0 = 1.0f; e1 = 1.0f; }
        else {
          float js = (float)(s + 1) - 25.5f;
          e0 = fmaf(a0, js, 1.0f);
          e1 = fmaf(a1, js, 1.0f);
        }
        const float* base = C + (size_t)row * ED + 2 * lane;
#pragma unroll
        for (int k = 0; k < 4; ++k) {
          float2 cv = *(const float2*)(base + (size_t)k * NV * ED);
          acc[gg][k].x = fmaf(e0, cv.x, acc[gg][k].x);
          acc[gg][k].y = fmaf(e1, cv.y, acc[gg][k].y);
        }
      }
    }
    __syncthreads();
  }

#pragma unroll
  for (int gg = 0; gg < 4; ++gg) {
    const int bm = bm0 + wave + 4 * gg;
#pragma unroll
    for (int k = 0; k < 4; ++k)
      *(float2*)(Mt + (size_t)k * BMD + (size_t)bm * ED + 2 * lane) = acc[gg][k];
  }
}

// ---------------------------------------------------------------------------
// Kernel B: per-batch hop loop, 512 thr/block, 1 block per b.
// KEY: MC of hop h == MA of hop h+1. Stage T0 into LDS once; per hop,
// PREFETCH T_{h+1} slice into 50 regs/thread (issued before scores, no use
// until after softmax -> latency fully hidden), compute o from regs, then
// write regs->LDS so the tile becomes the next hop's scores table.
// Serial global stage phases: 6 -> 1.
// ---------------------------------------------------------------------------
__global__ __launch_bounds__(512, 2) void hops_k(
    const int* __restrict__ query, const float* __restrict__ C,
    const float* __restrict__ Tw, const float* __restrict__ Tb,
    const float* __restrict__ Mt, float* __restrict__ U) {
  const int b = blockIdx.x;
  const int tid = threadIdx.x;                   // 0..511
  const int d = tid & 127;
  const int p = tid >> 7;                        // 0..3
  const int wave = tid >> 6, lane = tid & 63;
  __shared__ float tile[NM * ED];                // 102,400 B
  __shared__ float u[ED];
  __shared__ float part[512];
  __shared__ float sc[NM];
  __shared__ float o[ED];

  // ---- stage T0 -> LDS (6400 float4; 13 reg-buffered per thread)
  {
    const float4* s4 = (const float4*)(Mt + (size_t)b * NM * ED);
    float4* t4 = (float4*)tile;
    float4 st[13];
#pragma unroll
    for (int j = 0; j < 13; ++j) {
      int i = tid + 512 * j;
      st[j] = (i < NM * ED / 4) ? s4[i] : make_float4(0.f, 0.f, 0.f, 0.f);
    }
#pragma unroll
    for (int j = 0; j < 13; ++j) {
      int i = tid + 512 * j;
      if (i < NM * ED / 4) t4[i] = st[j];
    }
  }

  // ---- u0 = sum_s enc[s][d] * C0[query[b][s]][d] (reg-buffered)
  {
    const float ad = ((float)(d + 1) - 64.5f) * 6.25e-4f;
    int rows[13];
#pragma unroll
    for (int j = 0; j < 13; ++j) {
      int s = p + 4 * j;
      rows[j] = query[b * SS + (s < SS ? s : 0)];
    }
    float cv[13];
#pragma unroll
    for (int j = 0; j < 13; ++j)
      cv[j] = C[(size_t)rows[j] * ED + d];
    float accv = 0.f;
#pragma unroll
    for (int j = 0; j < 13; ++j) {
      int s = p + 4 * j;
      float e;
      if (s >= SS) e = 0.f;
      else if (s == SS - 1) e = 1.0f;
      else e = fmaf(ad, (float)(s + 1) - 25.5f, 1.0f);
      accv = fmaf(e, cv[j], accv);
    }
    part[tid] = accv;
  }
  __syncthreads();
  if (tid < ED)
    u[tid] = part[tid] + part[tid + 128] + part[tid + 256] + part[tid + 384];
  __syncthreads();

  for (int hop = 0; hop < 3; ++hop) {
    // ---- prefetch next table slice into regs (no use until o-phase)
    const float* Tn = Mt + (size_t)(hop + 1) * BMD + (size_t)b * NM * ED;
    float pf[50];
#pragma unroll
    for (int j = 0; j < 50; ++j)
      pf[j] = Tn[(size_t)(p + 4 * j) * ED + d];

    // ---- scores[m] = dot(tile[m], u)   (tile == T_hop)
    {
      float u0v = u[2 * lane], u1v = u[2 * lane + 1];
      for (int m = wave; m < NM; m += 16) {
        const int m2 = m + 8;
        const bool has2 = (m2 < NM);
        float2 r0 = *(const float2*)&tile[m * ED + 2 * lane];
        float pa = r0.x * u0v + r0.y * u1v;
        float pb = 0.f;
        if (has2) {
          float2 r1 = *(const float2*)&tile[m2 * ED + 2 * lane];
          pb = r1.x * u0v + r1.y * u1v;
        }
#pragma unroll
        for (int off = 32; off; off >>= 1) {
          pa += __shfl_xor(pa, off);
          pb += __shfl_xor(pb, off);
        }
        if (lane == 0) {
          sc[m] = pa;
          if (has2) sc[m2] = pb;
        }
      }
    }
    __syncthreads();

    // ---- softmax (wave shfl reductions)
    float v = (tid < NM) ? sc[tid] : -1e30f;
    {
      float t = v;
#pragma unroll
      for (int off = 32; off; off >>= 1) t = fmaxf(t, __shfl_xor(t, off));
      if (lane == 0) part[wave] = t;
    }
    __syncthreads();
    float mx = part[0];
#pragma unroll
    for (int w = 1; w < 8; ++w) mx = fmaxf(mx, part[w]);
    float ev = 0.f;
    if (tid < NM) { ev = __expf(v - mx); sc[tid] = ev; }
    {
      float t = ev;
#pragma unroll
      for (int off = 32; off; off >>= 1) t += __shfl_xor(t, off);
      if (lane == 0) part[8 + wave] = t;
    }
    __syncthreads();
    float tot = part[8];
#pragma unroll
    for (int w = 9; w < 16; ++w) tot += part[w];
    const float inv = 1.0f / tot;
    __syncthreads();   // all waves done reading tile + sc stable

    // ---- o partial from regs; simultaneously retile LDS with T_{hop+1}
    {
      float oacc = 0.f;
#pragma unroll
      for (int j = 0; j < 50; ++j)
        oacc = fmaf(sc[p + 4 * j], pf[j], oacc);
      part[tid] = oacc;
    }
    if (hop < 2) {
#pragma unroll
      for (int j = 0; j < 50; ++j)
        tile[(p + 4 * j) * ED + d] = pf[j];
    }
    __syncthreads();
    if (tid < ED)
      o[tid] = (part[tid] + part[tid + 128] + part[tid + 256] + part[tid + 384])
               * inv;
    __syncthreads();

    // ---- t = sigmoid(u @ Tw^T + Tb); u = (1-t)*u + o*t
    {
      const float4* twr = (const float4*)(Tw + (size_t)d * ED + p * 32);
      float4 tw4[8];
#pragma unroll
      for (int j = 0; j < 8; ++j) tw4[j] = twr[j];
      float tacc = 0.f;
#pragma unroll
      for (int j = 0; j < 8; ++j) {
        tacc = fmaf(u[p * 32 + 4 * j + 0], tw4[j].x, tacc);
        tacc = fmaf(u[p * 32 + 4 * j + 1], tw4[j].y, tacc);
        tacc = fmaf(u[p * 32 + 4 * j + 2], tw4[j].z, tacc);
        tacc = fmaf(u[p * 32 + 4 * j + 3], tw4[j].w, tacc);
      }
      part[tid] = tacc;
    }
    __syncthreads();
    if (tid < ED) {
      float dot = part[tid] + part[tid + 128] + part[tid + 256] + part[tid + 384]
                  + Tb[tid];
      float tk = 1.0f / (1.0f + __expf(-dot));
      u[tid] = (1.0f - tk) * u[tid] + o[tid] * tk;
    }
    __syncthreads();
  }
  if (tid < ED) U[(size_t)b * ED + tid] = u[tid];
}

// ---------------------------------------------------------------------------
// Kernel C: a_hat[b][v] = sum_d U[b][d] * C3[v][d]
// 391 blocks x (128b x 128v) tile: C3 read exactly once. Both operands
// transposed in LDS, stride 132 (float4-aligned). Thread computes 8b x 8v
// with 4 ds_read_b128 per d-iter -> VALU-bound, not LDS-bound.
// ---------------------------------------------------------------------------
#define OSTR 132
__global__ __launch_bounds__(256) void out_mm_k(
    const float* __restrict__ U, const float* __restrict__ C3,
    float* __restrict__ out) {
  __shared__ float ut[ED * OSTR];   // [d][b]  67,584 B
  __shared__ float ct[ED * OSTR];   // [d][v]  67,584 B
  const int tid = threadIdx.x;
  const int v0 = blockIdx.x * 128;
  const int vcnt = min(128, NV - v0);   // 128, or 80 on the last block

  // stage U transposed (16384 floats, 64/thread, 4 reg-buffered batches)
#pragma unroll
  for (int bt = 0; bt < 4; ++bt) {
    float tmp[16];
#pragma unroll
    for (int j = 0; j < 16; ++j)
      tmp[j] = U[tid + 256 * (bt * 16 + j)];
#pragma unroll
    for (int j = 0; j < 16; ++j) {
      int i = tid + 256 * (bt * 16 + j);
      ut[(i & 127) * OSTR + (i >> 7)] = tmp[j];
    }
  }
  // stage C3 tile transposed (zero-pad past vcnt)
#pragma unroll
  for (int bt = 0; bt < 4; ++bt) {
    float tmp[16];
#pragma unroll
    for (int j = 0; j < 16; ++j) {
      int i = tid + 256 * (bt * 16 + j);
      tmp[j] = (i < vcnt * ED) ? C3[(size_t)v0 * ED + i] : 0.f;
    }
#pragma unroll
    for (int j = 0; j < 16; ++j) {
      int i = tid + 256 * (bt * 16 + j);
      ct[(i & 127) * OSTR + (i >> 7)] = tmp[j];
    }
  }
  __syncthreads();

  const int vb = (tid & 15) * 8;    // 16 v-groups of 8
  const int bb = (tid >> 4) * 8;    // 16 b-groups of 8
  float acc[8][8];
#pragma unroll
  for (int i = 0; i < 8; ++i)
#pragma unroll
    for (int j = 0; j < 8; ++j) acc[i][j] = 0.f;

  for (int dd = 0; dd < ED; ++dd) {
    float4 c0 = *(const float4*)&ct[dd * OSTR + vb];
    float4 c1 = *(const float4*)&ct[dd * OSTR + vb + 4];
    float4 u0 = *(const float4*)&ut[dd * OSTR + bb];
    float4 u1 = *(const float4*)&ut[dd * OSTR + bb + 4];
    float cv[8] = {c0.x, c0.y, c0.z, c0.w, c1.x, c1.y, c1.z, c1.w};
    float uv[8] = {u0.x, u0.y, u0.z, u0.w, u1.x, u1.y, u1.z, u1.w};
#pragma unroll
    for (int i = 0; i < 8; ++i)
#pragma unroll
      for (int j = 0; j < 8; ++j) acc[i][j] = fmaf(uv[i], cv[j], acc[i][j]);
  }

  if (vcnt == 128) {
#pragma unroll
    for (int i = 0; i < 8; ++i) {
      float4 r0 = make_float4(acc[i][0], acc[i][1], acc[i][2], acc[i][3]);
      float4 r1 = make_float4(acc[i][4], acc[i][5], acc[i][6], acc[i][7]);
      float* op = &out[(size_t)(bb + i) * NV + v0 + vb];
      *(float4*)op = r0;
      *(float4*)(op + 4) = r1;
    }
  } else {
#pragma unroll
    for (int i = 0; i < 8; ++i)
      for (int j = 0; j < 8; ++j)
        if (v0 + vb + j < NV)
          out[(size_t)(bb + i) * NV + v0 + vb + j] = acc[i][j];
  }
}

// ---------------------------------------------------------------------------
extern "C" void kernel_launch(void* const* d_in, const int* in_sizes, int n_in,
                              void* d_out, int out_size, void* d_ws, size_t ws_size,
                              hipStream_t stream) {
  const int*   story = (const int*)d_in[0];   // [128,200,50]
  const int*   query = (const int*)d_in[1];   // [128,50]
  const float* C     = (const float*)d_in[2]; // [4,50000,128]
  const float* Tw    = (const float*)d_in[3]; // [128,128]
  const float* Tb    = (const float*)d_in[4]; // [128]
  float* out = (float*)d_out;                 // [128,50000]

  float* wsf = (float*)d_ws;
  float* Mt  = wsf;                           // 4 * BMD floats
  float* U   = wsf + (size_t)4 * BMD;         // 128*128 floats

  hipLaunchKernelGGL(story_embed_k, dim3(NB * NM / 16), dim3(256), 0, stream,
                     story, C, Mt);
  hipLaunchKernelGGL(hops_k, dim3(NB), dim3(512), 0, stream,
                     query, C, Tw, Tb, Mt, U);
  hipLaunchKernelGGL(out_mm_k, dim3((NV + 127) / 128), dim3(256), 0, stream,
                     U, C + (size_t)3 * NV * ED, out);
}

// Round 8
// 409.816 us; speedup vs baseline: 1.7127x; 1.0737x over previous
//
#include <hip/hip_runtime.h>
#include <cstdint>
#include <cstddef>

#define NV 50000
#define ED 128
#define SS 50
#define NB 128
#define NM 200
#define BMD (NB*NM*ED)   // 3,276,800 floats per table
#define NCH 32
#define CHD 1563         // ceil(50000/32)

typedef _Float16 f16x8 __attribute__((ext_vector_type(8)));
typedef _Float16 f16x4 __attribute__((ext_vector_type(4)));
typedef float    f32x4 __attribute__((ext_vector_type(4)));

// ---------------------------------------------------------------------------
// Kernel A: vocab-chunked gather-reduce (unchanged — ~92% of the ~3.4 TB/s
// miss-path roofline with FETCH at the 8-XCD compulsory floor).
// ---------------------------------------------------------------------------
__global__ __launch_bounds__(256) void story_embed_k(
    const int* __restrict__ story, const float* __restrict__ C,
    float* __restrict__ Mt) {
  const int wave = threadIdx.x >> 6;
  const int lane = threadIdx.x & 63;
  const int bm0 = blockIdx.x * 16;
  const int sl = (lane < SS) ? lane : (SS - 1);

  int idxg[4], cidg[4];
#pragma unroll
  for (int gg = 0; gg < 4; ++gg) {
    const int bm = bm0 + wave + 4 * gg;
    idxg[gg] = story[(size_t)bm * SS + sl];
    cidg[gg] = (lane < SS) ? (idxg[gg] / CHD) : -1;
  }
  const float a0 = ((float)(2*lane + 1) - 64.5f) * 6.25e-4f;
  const float a1 = ((float)(2*lane + 2) - 64.5f) * 6.25e-4f;
  float2 acc[4][4];
#pragma unroll
  for (int gg = 0; gg < 4; ++gg)
#pragma unroll
    for (int k = 0; k < 4; ++k) acc[gg][k] = make_float2(0.f, 0.f);

  for (int c = 0; c < NCH; ++c) {
#pragma unroll
    for (int gg = 0; gg < 4; ++gg) {
      unsigned long long mask = __ballot(cidg[gg] == c);
      while (mask) {
        const int s = __builtin_ctzll(mask);
        mask &= mask - 1;
        const int row = __shfl(idxg[gg], s);
        float e0, e1;
        if (s == SS - 1) { e0 = 1.0f; e1 = 1.0f; }
        else {
          float js = (float)(s + 1) - 25.5f;
          e0 = fmaf(a0, js, 1.0f);
          e1 = fmaf(a1, js, 1.0f);
        }
        const float* base = C + (size_t)row * ED + 2 * lane;
#pragma unroll
        for (int k = 0; k < 4; ++k) {
          float2 cv = *(const float2*)(base + (size_t)k * NV * ED);
          acc[gg][k].x = fmaf(e0, cv.x, acc[gg][k].x);
          acc[gg][k].y = fmaf(e1, cv.y, acc[gg][k].y);
        }
      }
    }
    __syncthreads();
  }

#pragma unroll
  for (int gg = 0; gg < 4; ++gg) {
    const int bm = bm0 + wave + 4 * gg;
#pragma unroll
    for (int k = 0; k < 4; ++k)
      *(float2*)(Mt + (size_t)k * BMD + (size_t)bm * ED + 2 * lane) = acc[gg][k];
  }
}

// ---------------------------------------------------------------------------
// Kernel B: per-batch hop loop (byte-identical to round 7 — control variable).
// ---------------------------------------------------------------------------
__global__ __launch_bounds__(512, 2) void hops_k(
    const int* __restrict__ query, const float* __restrict__ C,
    const float* __restrict__ Tw, const float* __restrict__ Tb,
    const float* __restrict__ Mt, float* __restrict__ U) {
  const int b = blockIdx.x;
  const int tid = threadIdx.x;                   // 0..511
  const int d = tid & 127;
  const int p = tid >> 7;                        // 0..3
  const int wave = tid >> 6, lane = tid & 63;
  __shared__ float tile[NM * ED];                // 102,400 B
  __shared__ float u[ED];
  __shared__ float part[512];
  __shared__ float sc[NM];
  __shared__ float o[ED];

  // ---- stage T0 -> LDS (6400 float4; 13 reg-buffered per thread)
  {
    const float4* s4 = (const float4*)(Mt + (size_t)b * NM * ED);
    float4* t4 = (float4*)tile;
    float4 st[13];
#pragma unroll
    for (int j = 0; j < 13; ++j) {
      int i = tid + 512 * j;
      st[j] = (i < NM * ED / 4) ? s4[i] : make_float4(0.f, 0.f, 0.f, 0.f);
    }
#pragma unroll
    for (int j = 0; j < 13; ++j) {
      int i = tid + 512 * j;
      if (i < NM * ED / 4) t4[i] = st[j];
    }
  }

  // ---- u0 = sum_s enc[s][d] * C0[query[b][s]][d] (reg-buffered)
  {
    const float ad = ((float)(d + 1) - 64.5f) * 6.25e-4f;
    int rows[13];
#pragma unroll
    for (int j = 0; j < 13; ++j) {
      int s = p + 4 * j;
      rows[j] = query[b * SS + (s < SS ? s : 0)];
    }
    float cv[13];
#pragma unroll
    for (int j = 0; j < 13; ++j)
      cv[j] = C[(size_t)rows[j] * ED + d];
    float accv = 0.f;
#pragma unroll
    for (int j = 0; j < 13; ++j) {
      int s = p + 4 * j;
      float e;
      if (s >= SS) e = 0.f;
      else if (s == SS - 1) e = 1.0f;
      else e = fmaf(ad, (float)(s + 1) - 25.5f, 1.0f);
      accv = fmaf(e, cv[j], accv);
    }
    part[tid] = accv;
  }
  __syncthreads();
  if (tid < ED)
    u[tid] = part[tid] + part[tid + 128] + part[tid + 256] + part[tid + 384];
  __syncthreads();

  for (int hop = 0; hop < 3; ++hop) {
    const float* Tn = Mt + (size_t)(hop + 1) * BMD + (size_t)b * NM * ED;
    float pf[50];
#pragma unroll
    for (int j = 0; j < 50; ++j)
      pf[j] = Tn[(size_t)(p + 4 * j) * ED + d];

    {
      float u0v = u[2 * lane], u1v = u[2 * lane + 1];
      for (int m = wave; m < NM; m += 16) {
        const int m2 = m + 8;
        const bool has2 = (m2 < NM);
        float2 r0 = *(const float2*)&tile[m * ED + 2 * lane];
        float pa = r0.x * u0v + r0.y * u1v;
        float pb = 0.f;
        if (has2) {
          float2 r1 = *(const float2*)&tile[m2 * ED + 2 * lane];
          pb = r1.x * u0v + r1.y * u1v;
        }
#pragma unroll
        for (int off = 32; off; off >>= 1) {
          pa += __shfl_xor(pa, off);
          pb += __shfl_xor(pb, off);
        }
        if (lane == 0) {
          sc[m] = pa;
          if (has2) sc[m2] = pb;
        }
      }
    }
    __syncthreads();

    float v = (tid < NM) ? sc[tid] : -1e30f;
    {
      float t = v;
#pragma unroll
      for (int off = 32; off; off >>= 1) t = fmaxf(t, __shfl_xor(t, off));
      if (lane == 0) part[wave] = t;
    }
    __syncthreads();
    float mx = part[0];
#pragma unroll
    for (int w = 1; w < 8; ++w) mx = fmaxf(mx, part[w]);
    float ev = 0.f;
    if (tid < NM) { ev = __expf(v - mx); sc[tid] = ev; }
    {
      float t = ev;
#pragma unroll
      for (int off = 32; off; off >>= 1) t += __shfl_xor(t, off);
      if (lane == 0) part[8 + wave] = t;
    }
    __syncthreads();
    float tot = part[8];
#pragma unroll
    for (int w = 9; w < 16; ++w) tot += part[w];
    const float inv = 1.0f / tot;
    __syncthreads();

    {
      float oacc = 0.f;
#pragma unroll
      for (int j = 0; j < 50; ++j)
        oacc = fmaf(sc[p + 4 * j], pf[j], oacc);
      part[tid] = oacc;
    }
    if (hop < 2) {
#pragma unroll
      for (int j = 0; j < 50; ++j)
        tile[(p + 4 * j) * ED + d] = pf[j];
    }
    __syncthreads();
    if (tid < ED)
      o[tid] = (part[tid] + part[tid + 128] + part[tid + 256] + part[tid + 384])
               * inv;
    __syncthreads();

    {
      const float4* twr = (const float4*)(Tw + (size_t)d * ED + p * 32);
      float4 tw4[8];
#pragma unroll
      for (int j = 0; j < 8; ++j) tw4[j] = twr[j];
      float tacc = 0.f;
#pragma unroll
      for (int j = 0; j < 8; ++j) {
        tacc = fmaf(u[p * 32 + 4 * j + 0], tw4[j].x, tacc);
        tacc = fmaf(u[p * 32 + 4 * j + 1], tw4[j].y, tacc);
        tacc = fmaf(u[p * 32 + 4 * j + 2], tw4[j].z, tacc);
        tacc = fmaf(u[p * 32 + 4 * j + 3], tw4[j].w, tacc);
      }
      part[tid] = tacc;
    }
    __syncthreads();
    if (tid < ED) {
      float dot = part[tid] + part[tid + 128] + part[tid + 256] + part[tid + 384]
                  + Tb[tid];
      float tk = 1.0f / (1.0f + __expf(-dot));
      u[tid] = (1.0f - tk) * u[tid] + o[tid] * tk;
    }
    __syncthreads();
  }
  if (tid < ED) U[(size_t)b * ED + tid] = u[tid];
}

// ---------------------------------------------------------------------------
// Kernel C0: C3 fp32 -> f16 (6.4M elems; thread = 8 elems, 16B store)
// ---------------------------------------------------------------------------
__global__ __launch_bounds__(256) void cvt_c3_k(
    const float* __restrict__ src, _Float16* __restrict__ dst) {
  const int i = blockIdx.x * 256 + threadIdx.x;   // f16x8 group, < 800000
  const float4* s4 = (const float4*)src;
  float4 f0 = s4[2 * i];
  float4 f1 = s4[2 * i + 1];
  f16x8 h;
  h[0] = (_Float16)f0.x; h[1] = (_Float16)f0.y;
  h[2] = (_Float16)f0.z; h[3] = (_Float16)f0.w;
  h[4] = (_Float16)f1.x; h[5] = (_Float16)f1.y;
  h[6] = (_Float16)f1.z; h[7] = (_Float16)f1.w;
  *(f16x8*)(dst + (size_t)8 * i) = h;
}

// ---------------------------------------------------------------------------
// Kernel C: a_hat = U @ C3^T via f16 MFMA (fp32 accumulate).
// Block = 4 waves, tile 64v x 128b; wave w: v-range blockIdx*64+w*16, all 8
// b-tiles. U converted to f16 in LDS (stride 136 -> conflict-free b128 reads).
// Layouts (m89-verified, dtype-independent):
//   A[m][k]: m=lane&15, k=quad*8+j   (U row fragment, 16B contiguous)
//   B[k][n]: n=lane&15, k=quad*8+j   (C3 row fragment, 16B contiguous)
//   D[r][n]: n=lane&15, r=quad*4+reg
// ---------------------------------------------------------------------------
__global__ __launch_bounds__(256) void out_mm_mfma_k(
    const float* __restrict__ U, const _Float16* __restrict__ C3h,
    float* __restrict__ out) {
  __shared__ _Float16 Ub[ED * 136];   // 34,816 B
  const int tid = threadIdx.x;

  // stage U -> f16 LDS (4096 float4 total; 16 per thread)
  {
    const float4* u4 = (const float4*)U;
#pragma unroll
    for (int j = 0; j < 16; ++j) {
      int i = tid + 256 * j;          // float4 index
      float4 f = u4[i];
      int row = i >> 5;               // 32 float4 per 128-float row
      int col = (i & 31) * 4;
      f16x4 h;
      h[0] = (_Float16)f.x; h[1] = (_Float16)f.y;
      h[2] = (_Float16)f.z; h[3] = (_Float16)f.w;
      *(f16x4*)&Ub[row * 136 + col] = h;
    }
  }
  __syncthreads();

  const int wave = tid >> 6, lane = tid & 63;
  const int n = lane & 15, q = lane >> 4;
  const int v = blockIdx.x * 64 + wave * 16 + n;
  const bool vok = (v < NV);

  f32x4 acc[8];
#pragma unroll
  for (int mt = 0; mt < 8; ++mt) acc[mt] = (f32x4){0.f, 0.f, 0.f, 0.f};

#pragma unroll
  for (int kt = 0; kt < 4; ++kt) {
    f16x8 bfrag = {};
    if (vok) bfrag = *(const f16x8*)(C3h + (size_t)v * ED + kt * 32 + q * 8);
#pragma unroll
    for (int mt = 0; mt < 8; ++mt) {
      f16x8 afrag = *(const f16x8*)&Ub[(mt * 16 + n) * 136 + kt * 32 + q * 8];
      acc[mt] = __builtin_amdgcn_mfma_f32_16x16x32_f16(afrag, bfrag, acc[mt],
                                                       0, 0, 0);
    }
  }

  if (vok) {
#pragma unroll
    for (int mt = 0; mt < 8; ++mt)
#pragma unroll
      for (int i = 0; i < 4; ++i)
        out[(size_t)(mt * 16 + q * 4 + i) * NV + v] = acc[mt][i];
  }
}

// ---------------------------------------------------------------------------
extern "C" void kernel_launch(void* const* d_in, const int* in_sizes, int n_in,
                              void* d_out, int out_size, void* d_ws, size_t ws_size,
                              hipStream_t stream) {
  const int*   story = (const int*)d_in[0];   // [128,200,50]
  const int*   query = (const int*)d_in[1];   // [128,50]
  const float* C     = (const float*)d_in[2]; // [4,50000,128]
  const float* Tw    = (const float*)d_in[3]; // [128,128]
  const float* Tb    = (const float*)d_in[4]; // [128]
  float* out = (float*)d_out;                 // [128,50000]

  float* wsf = (float*)d_ws;
  float*     Mt  = wsf;                                   // 4*BMD floats
  float*     U   = wsf + (size_t)4 * BMD;                 // 16384 floats
  _Float16*  C3h = (_Float16*)(wsf + (size_t)4 * BMD + NB * ED);

  hipLaunchKernelGGL(story_embed_k, dim3(NB * NM / 16), dim3(256), 0, stream,
                     story, C, Mt);
  hipLaunchKernelGGL(hops_k, dim3(NB), dim3(512), 0, stream,
                     query, C, Tw, Tb, Mt, U);
  hipLaunchKernelGGL(cvt_c3_k, dim3(NV * ED / 8 / 256), dim3(256), 0, stream,
                     C + (size_t)3 * NV * ED, C3h);
  hipLaunchKernelGGL(out_mm_mfma_k, dim3((NV + 63) / 64), dim3(256), 0, stream,
                     U, C3h, out);
}